// Round 3
// baseline (1478.167 us; speedup 1.0000x reference)
//
#include <hip/hip_runtime.h>
#include <math.h>

#define IDIM 2048
#define NE   64
#define TOPK 8
#define NB   16384
#define TM   64
#define DK   32
#define NTEAM 4
#define KT   512            // K per team
#define LSX  36             // stage row stride (floats)
#define TAU  5e-4f

// ws float layout: [0..63] f counts, [64..127] p sums, [128] z sum,
//                  [129] (int) flag count, [130..] (int) flagged row list
#define WS_CNT 129
#define WS_LIST 130

__device__ __forceinline__ float softplusf(float v) {
    return (v > 0.f) ? (v + log1pf(expf(-v))) : log1pf(expf(v));
}
__device__ __forceinline__ double softplus_d(double v) {
    return (v > 0.0) ? (v + log1p(exp(-v))) : log1p(exp(v));
}

__global__ void init_ws_kernel(float* ws) {
    int t = threadIdx.x;
    if (t < WS_LIST) ws[t] = 0.0f;   // zeros count (int 0 == float 0 bits)
}

// ---------------- pass 1: fp32 GEMM + gating + flag near-ties ----------------
__global__ __launch_bounds__(512, 2) void gate_main_kernel(
    const float* __restrict__ x, const float* __restrict__ noise,
    const float* __restrict__ Wg, const float* __restrict__ bg,
    const float* __restrict__ Wn,
    float* __restrict__ out_w, float* __restrict__ out_i,
    float* __restrict__ ws, int listCap)
{
    // float-indexed LDS map:
    //  stage: team*6912: sX[64][36], sWg[64][36] @+2304, sWn[64][36] @+4608  (4 teams, 27648 f)
    //  alias after main loop: xfer [384][33] @0 (12672 f)
    //                         sLogF [64][66] @12672, sNoisyF [64][66] @16896 (ends 21120 < 27648)
    //  sP @27648, sF @27712, sZ @27776
    __shared__ float smf[27780];

    const int t    = threadIdx.x;
    const int team = t >> 7;          // 0..3 (K quarter)
    const int lt   = t & 127;
    const int expcol = lt & 15;       // experts expcol + 16m, m=0..3
    const int rowg   = lt >> 4;       // rows rowg + 8j, j=0..7
    const int row0 = blockIdx.x * TM;

    float* stg = smf + team * 6912;
    float* sX  = stg;
    float* sWg = stg + 2304;
    float* sWn = stg + 4608;
    float* xfer    = smf;             // [384][33]
    float* sLogF   = smf + 12672;     // [64][66]
    float* sNoisyF = smf + 16896;     // [64][66]
    float* sP = smf + 27648;
    float* sF = smf + 27712;
    float* sZ = smf + 27776;

    if (t < NE) { sP[t] = 0.f; sF[t] = 0.f; }
    if (t == 0) sZ[0] = 0.f;

    float accg[8][4], accn[8][4];
    #pragma unroll
    for (int j = 0; j < 8; ++j)
        #pragma unroll
        for (int m = 0; m < 4; ++m) { accg[j][m] = 0.f; accn[j][m] = 0.f; }

    // staging: per thread 4 float4 per matrix; slot s covers row 16s+lr, col wc
    const int lr = lt >> 3;           // 0..15
    const int wc = (lt & 7) * 4;      // 0..28
    const float* xb[4]; const float* gb[4]; const float* nb[4];
    #pragma unroll
    for (int s = 0; s < 4; ++s) {
        int wr = 16 * s + lr;
        xb[s] = x  + (size_t)(row0 + wr) * IDIM + team * KT + wc;
        gb[s] = Wg + (size_t)wr * IDIM + team * KT + wc;
        nb[s] = Wn + (size_t)wr * IDIM + team * KT + wc;
    }
    float4 pX[4], pG[4], pN[4];

#define LOADTILE(kt) { \
    pX[0] = *(const float4*)(xb[0] + (kt)); pX[1] = *(const float4*)(xb[1] + (kt)); \
    pX[2] = *(const float4*)(xb[2] + (kt)); pX[3] = *(const float4*)(xb[3] + (kt)); \
    pG[0] = *(const float4*)(gb[0] + (kt)); pG[1] = *(const float4*)(gb[1] + (kt)); \
    pG[2] = *(const float4*)(gb[2] + (kt)); pG[3] = *(const float4*)(gb[3] + (kt)); \
    pN[0] = *(const float4*)(nb[0] + (kt)); pN[1] = *(const float4*)(nb[1] + (kt)); \
    pN[2] = *(const float4*)(nb[2] + (kt)); pN[3] = *(const float4*)(nb[3] + (kt)); }

#define STORETILE() { \
    *(float4*)&sX [(16*0 + lr) * LSX + wc] = pX[0]; *(float4*)&sX [(16*1 + lr) * LSX + wc] = pX[1]; \
    *(float4*)&sX [(16*2 + lr) * LSX + wc] = pX[2]; *(float4*)&sX [(16*3 + lr) * LSX + wc] = pX[3]; \
    *(float4*)&sWg[(16*0 + lr) * LSX + wc] = pG[0]; *(float4*)&sWg[(16*1 + lr) * LSX + wc] = pG[1]; \
    *(float4*)&sWg[(16*2 + lr) * LSX + wc] = pG[2]; *(float4*)&sWg[(16*3 + lr) * LSX + wc] = pG[3]; \
    *(float4*)&sWn[(16*0 + lr) * LSX + wc] = pN[0]; *(float4*)&sWn[(16*1 + lr) * LSX + wc] = pN[1]; \
    *(float4*)&sWn[(16*2 + lr) * LSX + wc] = pN[2]; *(float4*)&sWn[(16*3 + lr) * LSX + wc] = pN[3]; }

    LOADTILE(0); STORETILE(); __syncthreads();

    for (int tile = 0; tile < KT / DK; ++tile) {
        if (tile + 1 < KT / DK) LOADTILE((tile + 1) * DK);
        #pragma unroll
        for (int kk = 0; kk < DK; kk += 4) {
            float4 xv[8], gv[4], nv[4];
            #pragma unroll
            for (int j = 0; j < 8; ++j) xv[j] = *(const float4*)&sX[(rowg + 8 * j) * LSX + kk];
            #pragma unroll
            for (int m = 0; m < 4; ++m) {
                gv[m] = *(const float4*)&sWg[(expcol + 16 * m) * LSX + kk];
                nv[m] = *(const float4*)&sWn[(expcol + 16 * m) * LSX + kk];
            }
            #pragma unroll
            for (int q = 0; q < 4; ++q) {
                float gq[4], nq[4];
                #pragma unroll
                for (int m = 0; m < 4; ++m) { gq[m] = ((float*)&gv[m])[q]; nq[m] = ((float*)&nv[m])[q]; }
                #pragma unroll
                for (int j = 0; j < 8; ++j) {
                    float xq = ((float*)&xv[j])[q];
                    #pragma unroll
                    for (int m = 0; m < 4; ++m) {
                        accg[j][m] = fmaf(xq, gq[m], accg[j][m]);
                        accn[j][m] = fmaf(xq, nq[m], accn[j][m]);
                    }
                }
            }
        }
        __syncthreads();
        if (tile + 1 < KT / DK) { STORETILE(); __syncthreads(); }
    }

    // ---- combine 4 teams: phase A (logits), phase B (noise pre-act) ----
    if (team != 0) {
        float* xf = xfer + ((team - 1) * 128 + lt) * 33;
        #pragma unroll
        for (int j = 0; j < 8; ++j)
            #pragma unroll
            for (int m = 0; m < 4; ++m) xf[j * 4 + m] = accg[j][m];
    }
    __syncthreads();
    if (team == 0) {
        #pragma unroll
        for (int j = 0; j < 8; ++j) {
            int r = rowg + 8 * j;
            #pragma unroll
            for (int m = 0; m < 4; ++m) {
                int e = expcol + 16 * m;
                float g = accg[j][m]
                        + xfer[(lt) * 33 + j * 4 + m]
                        + xfer[(128 + lt) * 33 + j * 4 + m]
                        + xfer[(256 + lt) * 33 + j * 4 + m];
                sLogF[r * 66 + e] = g + bg[e];
            }
        }
    }
    __syncthreads();
    if (team != 0) {
        float* xf = xfer + ((team - 1) * 128 + lt) * 33;
        #pragma unroll
        for (int j = 0; j < 8; ++j)
            #pragma unroll
            for (int m = 0; m < 4; ++m) xf[j * 4 + m] = accn[j][m];
    }
    __syncthreads();
    if (team == 0) {
        #pragma unroll
        for (int j = 0; j < 8; ++j) {
            int r = rowg + 8 * j;
            int grow = row0 + r;
            #pragma unroll
            for (int m = 0; m < 4; ++m) {
                int e = expcol + 16 * m;
                float n = accn[j][m]
                        + xfer[(lt) * 33 + j * 4 + m]
                        + xfer[(128 + lt) * 33 + j * 4 + m]
                        + xfer[(256 + lt) * 33 + j * 4 + m];
                float sp = softplusf(n);
                float nz = noise[(size_t)grow * NE + e];
                sNoisyF[r * 66 + e] = fmaf(nz, sp, sLogF[r * 66 + e]);
            }
        }
    }
    __syncthreads();

    // ---- wave-parallel epilogue: 8 waves x 8 rows, lane = expert ----
    const int wv = t >> 6, lane = t & 63;
    float pacc = 0.f, zacc = 0.f;

    #pragma unroll 1
    for (int rr = 0; rr < 8; ++rr) {
        const int r = wv * 8 + rr;
        const int grow = row0 + r;
        float vcur = sNoisyF[r * 66 + lane];
        float lg   = sLogF[r * 66 + lane];

        float tkv[9]; int tki[9];
        #pragma unroll
        for (int k = 0; k < 9; ++k) {
            float mv = vcur; int mi = lane;
            #pragma unroll
            for (int o = 32; o > 0; o >>= 1) {
                float ov = __shfl_xor(mv, o);
                int   oi = __shfl_xor(mi, o);
                if (ov > mv || (ov == mv && oi < mi)) { mv = ov; mi = oi; }
            }
            tkv[k] = mv; tki[k] = mi;
            if (lane == mi) vcur = -1e30f;
        }

        // softmax over top-8 (fp32)
        float m0 = tkv[0], s = 0.f, w[TOPK];
        #pragma unroll
        for (int k = 0; k < TOPK; ++k) { w[k] = expf(tkv[k] - m0); s += w[k]; }
        float inv = 1.f / s;
        float myw = 0.f; int myi = 0;
        #pragma unroll
        for (int k = 0; k < TOPK; ++k)
            if (lane == k) { myw = w[k] * inv; myi = tki[k]; }
        if (lane < TOPK) {
            out_w[(size_t)grow * TOPK + lane] = myw;
            out_i[(size_t)grow * TOPK + lane] = (float)myi;
        }

        if (lane == 0) {
            atomicAdd(&sF[tki[0]], 1.f);
            float ming = 1e30f;
            #pragma unroll
            for (int k = 0; k < 8; ++k) ming = fminf(ming, tkv[k] - tkv[k + 1]);
            if (ming < TAU) {
                int slot = atomicAdd((int*)&ws[WS_CNT], 1);
                if (slot < listCap) ((int*)ws)[WS_LIST + slot] = grow;
            }
        }

        // p = softmax(logits) contribution, z = lse^2 (fp32)
        float rm = lg;
        #pragma unroll
        for (int o = 32; o > 0; o >>= 1) rm = fmaxf(rm, __shfl_xor(rm, o));
        float pe = expf(lg - rm);
        float ssum = pe;
        #pragma unroll
        for (int o = 32; o > 0; o >>= 1) ssum += __shfl_xor(ssum, o);
        pacc += pe / ssum;
        if (lane == 0) { float lse = rm + logf(ssum); zacc += lse * lse; }
    }

    atomicAdd(&sP[lane], pacc);
    if (lane == 0) atomicAdd(sZ, zacc);
    __syncthreads();
    if (t < NE) {
        atomicAdd(&ws[t],      sF[t]);
        atomicAdd(&ws[NE + t], sP[t]);
    }
    if (t == 0) atomicAdd(&ws[2 * NE], sZ[0]);
}

// ---------------- pass 2: fp64 recheck of flagged rows (matches R1 math) ----------------
__global__ __launch_bounds__(256) void recheck_kernel(
    const float* __restrict__ x, const float* __restrict__ noise,
    const float* __restrict__ Wg, const float* __restrict__ bg,
    const float* __restrict__ Wn,
    float* __restrict__ out_w, float* __restrict__ out_i,
    const float* __restrict__ ws, int listCap)
{
    __shared__ double sRed[256 * 4];
    const int* wsi = (const int*)ws;
    int cnt = wsi[WS_CNT];
    if (cnt > listCap) cnt = listCap;
    if (cnt <= 0) return;

    const int t = threadIdx.x;
    const int e128 = t & 127;         // 0..63: Wg expert; 64..127: Wn expert-64
    const int half = t >> 7;          // K half: [half*1024, +1024)

    const float* wr = (e128 < 64) ? (Wg + (size_t)e128 * IDIM)
                                  : (Wn + (size_t)(e128 - 64) * IDIM);
    wr += half * 1024;

    for (int base = blockIdx.x * 4; base < cnt; base += gridDim.x * 4) {
        int rows[4];
        #pragma unroll
        for (int i = 0; i < 4; ++i) {
            int ii = base + i;
            rows[i] = wsi[WS_LIST + (ii < cnt ? ii : cnt - 1)];
        }
        const float* xr0 = x + (size_t)rows[0] * IDIM + half * 1024;
        const float* xr1 = x + (size_t)rows[1] * IDIM + half * 1024;
        const float* xr2 = x + (size_t)rows[2] * IDIM + half * 1024;
        const float* xr3 = x + (size_t)rows[3] * IDIM + half * 1024;

        double a0 = 0, a1 = 0, a2 = 0, a3 = 0;
        for (int k = 0; k < 1024; k += 4) {
            float4 wv = *(const float4*)(wr + k);
            float4 x0 = *(const float4*)(xr0 + k);
            float4 x1 = *(const float4*)(xr1 + k);
            float4 x2 = *(const float4*)(xr2 + k);
            float4 x3 = *(const float4*)(xr3 + k);
            #pragma unroll
            for (int q = 0; q < 4; ++q) {
                double wd = (double)((float*)&wv)[q];
                a0 = fma((double)((float*)&x0)[q], wd, a0);
                a1 = fma((double)((float*)&x1)[q], wd, a1);
                a2 = fma((double)((float*)&x2)[q], wd, a2);
                a3 = fma((double)((float*)&x3)[q], wd, a3);
            }
        }
        sRed[t * 4 + 0] = a0; sRed[t * 4 + 1] = a1;
        sRed[t * 4 + 2] = a2; sRed[t * 4 + 3] = a3;
        __syncthreads();
        if (t < 128) {
            #pragma unroll
            for (int i = 0; i < 4; ++i) sRed[t * 4 + i] += sRed[(t + 128) * 4 + i];
        }
        __syncthreads();
        if (t < 64) {
            const int lane = t;
            double bgl = (double)bg[lane];
            #pragma unroll 1
            for (int i = 0; i < 4; ++i) {
                int row = rows[i];
                double g = sRed[lane * 4 + i];
                double n = sRed[(64 + lane) * 4 + i];
                double lg = g + bgl;
                double nz = (double)noise[(size_t)row * NE + lane];
                double vcur = fma(nz, softplus_d(n), lg);

                double tkv[TOPK]; int tki[TOPK];
                #pragma unroll
                for (int k = 0; k < TOPK; ++k) {
                    double mv = vcur; int mi = lane;
                    #pragma unroll
                    for (int o = 32; o > 0; o >>= 1) {
                        double ov = __shfl_xor(mv, o);
                        int    oi = __shfl_xor(mi, o);
                        if (ov > mv || (ov == mv && oi < mi)) { mv = ov; mi = oi; }
                    }
                    tkv[k] = mv; tki[k] = mi;
                    if (lane == mi) vcur = -1e300;
                }
                double m0 = tkv[0], s = 0.0, wk[TOPK];
                #pragma unroll
                for (int k = 0; k < TOPK; ++k) { wk[k] = exp(tkv[k] - m0); s += wk[k]; }
                double inv = 1.0 / s;
                float myw = 0.f; int myi = 0;
                #pragma unroll
                for (int k = 0; k < TOPK; ++k)
                    if (lane == k) { myw = (float)(wk[k] * inv); myi = tki[k]; }
                if (lane < TOPK) {
                    out_w[(size_t)row * TOPK + lane] = myw;
                    out_i[(size_t)row * TOPK + lane] = (float)myi;
                }
            }
        }
        __syncthreads();
    }
}

__global__ void finalize_kernel(const float* __restrict__ ws, float* __restrict__ out) {
    int t = threadIdx.x; // 64 threads, one wave
    float v = (ws[t] / (float)NB) * (ws[NE + t] / (float)NB);
    #pragma unroll
    for (int o = 32; o > 0; o >>= 1) v += __shfl_down(v, o);
    if (t == 0) {
        out[2 * NB * TOPK]     = (float)NE * v;
        out[2 * NB * TOPK + 1] = ws[2 * NE] / (float)NB;
    }
}

extern "C" void kernel_launch(void* const* d_in, const int* in_sizes, int n_in,
                              void* d_out, int out_size, void* d_ws, size_t ws_size,
                              hipStream_t stream) {
    const float* x     = (const float*)d_in[0];
    const float* noise = (const float*)d_in[1];
    const float* Wg    = (const float*)d_in[2];
    const float* bg    = (const float*)d_in[3];
    const float* Wn    = (const float*)d_in[4];
    float* out = (float*)d_out;
    float* ws  = (float*)d_ws;

    long cap = (long)(ws_size / 4) - WS_LIST;
    int listCap = (int)(cap < 0 ? 0 : (cap > NB ? NB : cap));

    hipLaunchKernelGGL(init_ws_kernel, dim3(1), dim3(256), 0, stream, ws);
    hipLaunchKernelGGL(gate_main_kernel, dim3(NB / TM), dim3(512), 0, stream,
                       x, noise, Wg, bg, Wn,
                       out, out + (size_t)NB * TOPK, ws, listCap);
    hipLaunchKernelGGL(recheck_kernel, dim3(256), dim3(256), 0, stream,
                       x, noise, Wg, bg, Wn,
                       out, out + (size_t)NB * TOPK, ws, listCap);
    hipLaunchKernelGGL(finalize_kernel, dim3(1), dim3(64), 0, stream, ws, out);
}

// Round 4
// 287.477 us; speedup vs baseline: 5.1419x; 5.1419x over previous
//
#include <hip/hip_runtime.h>
#include <math.h>

#define IDIM 2048
#define NE   64
#define TOPK 8
#define NB   16384
#define TM   32            // rows per block
#define DK   16            // K per staging tile
#define KT   512           // K per team
#define LSX  20            // LDS row stride (floats) = DK + 4
#define TAU  5e-4f

// ws float layout: [0..63] f counts, [64..127] p sums, [128] z sum,
//                  [129] (int) flag count, [130..] (int) flagged row list
#define WS_CNT 129
#define WS_LIST 130

__device__ __forceinline__ float softplusf(float v) {
    return (v > 0.f) ? (v + log1pf(expf(-v))) : log1pf(expf(v));
}
__device__ __forceinline__ double softplus_d(double v) {
    return (v > 0.0) ? (v + log1p(exp(-v))) : log1p(exp(v));
}

__global__ void init_ws_kernel(float* ws) {
    int t = threadIdx.x;
    if (t < WS_LIST) ws[t] = 0.0f;
}

// ---------------- pass 1: fp32 GEMM + gating + flag near-ties ----------------
// LDS float map (12929 floats = 51.7 KB):
//   staging: team*3200: sX[32][20], sWg[64][20] @+640, sWn[64][20] @+1920
//   alias after main loop: xfer[384][17] @0 (6528 f)
//                          sLogF[32][66] @6528, sNoisyF[32][66] @8640
//   sP @12800, sF @12864, sZ @12928   (outside staging, never aliased)
__global__ __launch_bounds__(512, 2) void gate_main_kernel(
    const float* __restrict__ x, const float* __restrict__ noise,
    const float* __restrict__ Wg, const float* __restrict__ bg,
    const float* __restrict__ Wn,
    float* __restrict__ out_w, float* __restrict__ out_i,
    float* __restrict__ ws, int listCap)
{
    __shared__ float smf[12929];

    const int t    = threadIdx.x;
    const int team = t >> 7;          // 0..3 (K quarter)
    const int lt   = t & 127;
    const int expcol = lt & 15;       // experts expcol + 16m, m=0..3
    const int rowg   = lt >> 4;       // rows rowg + 8j, j=0..3
    const int row0 = blockIdx.x * TM;

    float* stg = smf + team * 3200;
    float* sX  = stg;
    float* sWg = stg + 640;
    float* sWn = stg + 1920;
    float* xfer    = smf;             // [384][17]
    float* sLogF   = smf + 6528;      // [32][66]
    float* sNoisyF = smf + 8640;      // [32][66]
    float* sP = smf + 12800;
    float* sF = smf + 12864;
    float* sZ = smf + 12928;

    if (t < NE) { sP[t] = 0.f; sF[t] = 0.f; }
    if (t == 0) sZ[0] = 0.f;

    float accg[4][4], accn[4][4];
    #pragma unroll
    for (int j = 0; j < 4; ++j)
        #pragma unroll
        for (int m = 0; m < 4; ++m) { accg[j][m] = 0.f; accn[j][m] = 0.f; }

    // staging: 5 float4 per thread per tile
    const int lr = lt >> 2;           // 0..31
    const int wc = (lt & 3) * 4;      // 0,4,8,12
    const float* xp  = x  + (size_t)(row0 + lr) * IDIM + team * KT + wc;
    const float* gp0 = Wg + (size_t)lr        * IDIM + team * KT + wc;
    const float* gp1 = Wg + (size_t)(lr + 32) * IDIM + team * KT + wc;
    const float* np0 = Wn + (size_t)lr        * IDIM + team * KT + wc;
    const float* np1 = Wn + (size_t)(lr + 32) * IDIM + team * KT + wc;

    for (int k0 = 0; k0 < KT; k0 += DK) {
        float4 va = *(const float4*)(xp  + k0);
        float4 vb = *(const float4*)(gp0 + k0);
        float4 vc = *(const float4*)(gp1 + k0);
        float4 vd = *(const float4*)(np0 + k0);
        float4 ve = *(const float4*)(np1 + k0);
        __syncthreads();   // previous tile's reads complete
        *(float4*)&sX [lr * LSX + wc]        = va;
        *(float4*)&sWg[lr * LSX + wc]        = vb;
        *(float4*)&sWg[(lr + 32) * LSX + wc] = vc;
        *(float4*)&sWn[lr * LSX + wc]        = vd;
        *(float4*)&sWn[(lr + 32) * LSX + wc] = ve;
        __syncthreads();

        #pragma unroll 1
        for (int kk = 0; kk < DK; kk += 4) {
            float4 xv[4], gv[4], nv[4];
            #pragma unroll
            for (int j = 0; j < 4; ++j)
                xv[j] = *(const float4*)&sX[(rowg + 8 * j) * LSX + kk];
            #pragma unroll
            for (int m = 0; m < 4; ++m) {
                gv[m] = *(const float4*)&sWg[(expcol + 16 * m) * LSX + kk];
                nv[m] = *(const float4*)&sWn[(expcol + 16 * m) * LSX + kk];
            }
            #pragma unroll
            for (int q = 0; q < 4; ++q) {
                float gq[4], nq[4];
                #pragma unroll
                for (int m = 0; m < 4; ++m) { gq[m] = ((float*)&gv[m])[q]; nq[m] = ((float*)&nv[m])[q]; }
                #pragma unroll
                for (int j = 0; j < 4; ++j) {
                    float xq = ((float*)&xv[j])[q];
                    #pragma unroll
                    for (int m = 0; m < 4; ++m) {
                        accg[j][m] = fmaf(xq, gq[m], accg[j][m]);
                        accn[j][m] = fmaf(xq, nq[m], accn[j][m]);
                    }
                }
            }
        }
    }
    __syncthreads();   // staging dead; safe to alias

    // ---- combine 4 teams: phase A (logits), phase B (noise pre-act) ----
    if (team != 0) {
        float* xf = xfer + ((team - 1) * 128 + lt) * 17;
        #pragma unroll
        for (int j = 0; j < 4; ++j)
            #pragma unroll
            for (int m = 0; m < 4; ++m) xf[j * 4 + m] = accg[j][m];
    }
    __syncthreads();
    if (team == 0) {
        #pragma unroll
        for (int j = 0; j < 4; ++j) {
            int r = rowg + 8 * j;
            #pragma unroll
            for (int m = 0; m < 4; ++m) {
                int e = expcol + 16 * m;
                float g = accg[j][m]
                        + xfer[(lt) * 17 + j * 4 + m]
                        + xfer[(128 + lt) * 17 + j * 4 + m]
                        + xfer[(256 + lt) * 17 + j * 4 + m];
                sLogF[r * 66 + e] = g + bg[e];
            }
        }
    }
    __syncthreads();
    if (team != 0) {
        float* xf = xfer + ((team - 1) * 128 + lt) * 17;
        #pragma unroll
        for (int j = 0; j < 4; ++j)
            #pragma unroll
            for (int m = 0; m < 4; ++m) xf[j * 4 + m] = accn[j][m];
    }
    __syncthreads();
    if (team == 0) {
        #pragma unroll
        for (int j = 0; j < 4; ++j) {
            int r = rowg + 8 * j;
            int grow = row0 + r;
            #pragma unroll
            for (int m = 0; m < 4; ++m) {
                int e = expcol + 16 * m;
                float n = accn[j][m]
                        + xfer[(lt) * 17 + j * 4 + m]
                        + xfer[(128 + lt) * 17 + j * 4 + m]
                        + xfer[(256 + lt) * 17 + j * 4 + m];
                float sp = softplusf(n);
                float nz = noise[(size_t)grow * NE + e];
                sNoisyF[r * 66 + e] = fmaf(nz, sp, sLogF[r * 66 + e]);
            }
        }
    }
    __syncthreads();

    // ---- wave-parallel epilogue: 8 waves x 4 rows, lane = expert ----
    const int wv = t >> 6, lane = t & 63;
    float pacc = 0.f, zacc = 0.f;

    #pragma unroll 1
    for (int rr = 0; rr < 4; ++rr) {
        const int r = wv * 4 + rr;
        const int grow = row0 + r;
        float vcur = sNoisyF[r * 66 + lane];
        float lg   = sLogF[r * 66 + lane];

        float tkv[9]; int tki[9];
        #pragma unroll
        for (int k = 0; k < 9; ++k) {
            float mv = vcur; int mi = lane;
            #pragma unroll
            for (int o = 32; o > 0; o >>= 1) {
                float ov = __shfl_xor(mv, o);
                int   oi = __shfl_xor(mi, o);
                if (ov > mv || (ov == mv && oi < mi)) { mv = ov; mi = oi; }
            }
            tkv[k] = mv; tki[k] = mi;
            if (lane == mi) vcur = -1e30f;
        }

        float m0 = tkv[0], s = 0.f, w[TOPK];
        #pragma unroll
        for (int k = 0; k < TOPK; ++k) { w[k] = expf(tkv[k] - m0); s += w[k]; }
        float inv = 1.f / s;
        float myw = 0.f; int myi = 0;
        #pragma unroll
        for (int k = 0; k < TOPK; ++k)
            if (lane == k) { myw = w[k] * inv; myi = tki[k]; }
        if (lane < TOPK) {
            out_w[(size_t)grow * TOPK + lane] = myw;
            out_i[(size_t)grow * TOPK + lane] = (float)myi;
        }

        if (lane == 0) {
            atomicAdd(&sF[tki[0]], 1.f);
            float ming = 1e30f;
            #pragma unroll
            for (int k = 0; k < 8; ++k) ming = fminf(ming, tkv[k] - tkv[k + 1]);
            if (ming < TAU) {
                int slot = atomicAdd((int*)&ws[WS_CNT], 1);
                if (slot < listCap) ((int*)ws)[WS_LIST + slot] = grow;
            }
        }

        float rm = lg;
        #pragma unroll
        for (int o = 32; o > 0; o >>= 1) rm = fmaxf(rm, __shfl_xor(rm, o));
        float pe = expf(lg - rm);
        float ssum = pe;
        #pragma unroll
        for (int o = 32; o > 0; o >>= 1) ssum += __shfl_xor(ssum, o);
        pacc += pe / ssum;
        if (lane == 0) { float lse = rm + logf(ssum); zacc += lse * lse; }
    }

    atomicAdd(&sP[lane], pacc);
    if (lane == 0) atomicAdd(sZ, zacc);
    __syncthreads();
    if (t < NE) {
        atomicAdd(&ws[t],      sF[t]);
        atomicAdd(&ws[NE + t], sP[t]);
    }
    if (t == 0) atomicAdd(&ws[2 * NE], sZ[0]);
}

// ---------------- pass 2: fp64 recheck of flagged rows ----------------
__global__ __launch_bounds__(256) void recheck_kernel(
    const float* __restrict__ x, const float* __restrict__ noise,
    const float* __restrict__ Wg, const float* __restrict__ bg,
    const float* __restrict__ Wn,
    float* __restrict__ out_w, float* __restrict__ out_i,
    const float* __restrict__ ws, int listCap)
{
    __shared__ double sRed[256 * 4];
    const int* wsi = (const int*)ws;
    int cnt = wsi[WS_CNT];
    if (cnt > listCap) cnt = listCap;
    if (cnt <= 0) return;

    const int t = threadIdx.x;
    const int e128 = t & 127;         // 0..63: Wg expert; 64..127: Wn expert-64
    const int half = t >> 7;          // K half

    const float* wr = (e128 < 64) ? (Wg + (size_t)e128 * IDIM)
                                  : (Wn + (size_t)(e128 - 64) * IDIM);
    wr += half * 1024;

    for (int base = blockIdx.x * 4; base < cnt; base += gridDim.x * 4) {
        int rows[4];
        #pragma unroll
        for (int i = 0; i < 4; ++i) {
            int ii = base + i;
            rows[i] = wsi[WS_LIST + (ii < cnt ? ii : cnt - 1)];
        }
        const float* xr0 = x + (size_t)rows[0] * IDIM + half * 1024;
        const float* xr1 = x + (size_t)rows[1] * IDIM + half * 1024;
        const float* xr2 = x + (size_t)rows[2] * IDIM + half * 1024;
        const float* xr3 = x + (size_t)rows[3] * IDIM + half * 1024;

        double a0 = 0, a1 = 0, a2 = 0, a3 = 0;
        for (int k = 0; k < 1024; k += 4) {
            float4 wv = *(const float4*)(wr + k);
            float4 x0 = *(const float4*)(xr0 + k);
            float4 x1 = *(const float4*)(xr1 + k);
            float4 x2 = *(const float4*)(xr2 + k);
            float4 x3 = *(const float4*)(xr3 + k);
            #pragma unroll
            for (int q = 0; q < 4; ++q) {
                double wd = (double)((float*)&wv)[q];
                a0 = fma((double)((float*)&x0)[q], wd, a0);
                a1 = fma((double)((float*)&x1)[q], wd, a1);
                a2 = fma((double)((float*)&x2)[q], wd, a2);
                a3 = fma((double)((float*)&x3)[q], wd, a3);
            }
        }
        sRed[t * 4 + 0] = a0; sRed[t * 4 + 1] = a1;
        sRed[t * 4 + 2] = a2; sRed[t * 4 + 3] = a3;
        __syncthreads();
        if (t < 128) {
            #pragma unroll
            for (int i = 0; i < 4; ++i) sRed[t * 4 + i] += sRed[(t + 128) * 4 + i];
        }
        __syncthreads();
        if (t < 64) {
            const int lane = t;
            double bgl = (double)bg[lane];
            #pragma unroll 1
            for (int i = 0; i < 4; ++i) {
                int row = rows[i];
                double g = sRed[lane * 4 + i];
                double n = sRed[(64 + lane) * 4 + i];
                double lg = g + bgl;
                double nz = (double)noise[(size_t)row * NE + lane];
                double vcur = fma(nz, softplus_d(n), lg);

                double tkv[TOPK]; int tki[TOPK];
                #pragma unroll
                for (int k = 0; k < TOPK; ++k) {
                    double mv = vcur; int mi = lane;
                    #pragma unroll
                    for (int o = 32; o > 0; o >>= 1) {
                        double ov = __shfl_xor(mv, o);
                        int    oi = __shfl_xor(mi, o);
                        if (ov > mv || (ov == mv && oi < mi)) { mv = ov; mi = oi; }
                    }
                    tkv[k] = mv; tki[k] = mi;
                    if (lane == mi) vcur = -1e300;
                }
                double m0 = tkv[0], s = 0.0, wk[TOPK];
                #pragma unroll
                for (int k = 0; k < TOPK; ++k) { wk[k] = exp(tkv[k] - m0); s += wk[k]; }
                double inv = 1.0 / s;
                float myw = 0.f; int myi = 0;
                #pragma unroll
                for (int k = 0; k < TOPK; ++k)
                    if (lane == k) { myw = (float)(wk[k] * inv); myi = tki[k]; }
                if (lane < TOPK) {
                    out_w[(size_t)row * TOPK + lane] = myw;
                    out_i[(size_t)row * TOPK + lane] = (float)myi;
                }
            }
        }
        __syncthreads();
    }
}

__global__ void finalize_kernel(const float* __restrict__ ws, float* __restrict__ out) {
    int t = threadIdx.x; // 64 threads, one wave
    float v = (ws[t] / (float)NB) * (ws[NE + t] / (float)NB);
    #pragma unroll
    for (int o = 32; o > 0; o >>= 1) v += __shfl_down(v, o);
    if (t == 0) {
        out[2 * NB * TOPK]     = (float)NE * v;
        out[2 * NB * TOPK + 1] = ws[2 * NE] / (float)NB;
    }
}

extern "C" void kernel_launch(void* const* d_in, const int* in_sizes, int n_in,
                              void* d_out, int out_size, void* d_ws, size_t ws_size,
                              hipStream_t stream) {
    const float* x     = (const float*)d_in[0];
    const float* noise = (const float*)d_in[1];
    const float* Wg    = (const float*)d_in[2];
    const float* bg    = (const float*)d_in[3];
    const float* Wn    = (const float*)d_in[4];
    float* out = (float*)d_out;
    float* ws  = (float*)d_ws;

    long cap = (long)(ws_size / 4) - WS_LIST;
    int listCap = (int)(cap < 0 ? 0 : (cap > NB ? NB : cap));

    hipLaunchKernelGGL(init_ws_kernel, dim3(1), dim3(256), 0, stream, ws);
    hipLaunchKernelGGL(gate_main_kernel, dim3(NB / TM), dim3(512), 0, stream,
                       x, noise, Wg, bg, Wn,
                       out, out + (size_t)NB * TOPK, ws, listCap);
    hipLaunchKernelGGL(recheck_kernel, dim3(256), dim3(256), 0, stream,
                       x, noise, Wg, bg, Wn,
                       out, out + (size_t)NB * TOPK, ws, listCap);
    hipLaunchKernelGGL(finalize_kernel, dim3(1), dim3(64), 0, stream, ws, out);
}